// Round 1
// baseline (15849.019 us; speedup 1.0000x reference)
//
#include <hip/hip_runtime.h>
#include <stdint.h>

typedef __attribute__((ext_vector_type(8))) short short8;
typedef __attribute__((ext_vector_type(4))) float floatx4;
typedef unsigned short u16;
typedef unsigned int u32;

constexpr int BSZ = 64;     // batch
constexpr int SEQT = 512;   // encoder timesteps
constexpr int FIN = 64;     // input features F
constexpr int HID = 512;    // hidden H
constexpr int NG = 2048;    // 4*H gate rows
constexpr int FUTL = 96;    // decoder steps
constexpr int K0 = FIN + HID;   // 576  (layer-0 concat K)
constexpr int K1 = HID + HID;   // 1024 (layer-1 concat K)
constexpr int K0P = K0 + 8;     // padded LDS row stride for layer-0 W
constexpr int NBLK = 256;
constexpr int NTHR = 256;

// ---------------- workspace layout (bytes) ----------------
constexpr size_t S_W0 = (size_t)NG * K0 * 2;
constexpr size_t S_W1 = (size_t)NG * K1 * 2;
constexpr size_t S_FC = (size_t)FIN * HID * 2;
constexpr size_t S_X  = (size_t)SEQT * BSZ * FIN * 2;
constexpr size_t S_DX = (size_t)2 * BSZ * FIN * 2;
constexpr size_t S_H  = (size_t)2 * BSZ * HID * 2;
constexpr size_t S_C  = (size_t)BSZ * HID * 4;

constexpr size_t OFF_WHI_E0 = 0;
constexpr size_t OFF_WLO_E0 = OFF_WHI_E0 + S_W0;
constexpr size_t OFF_WHI_E1 = OFF_WLO_E0 + S_W0;
constexpr size_t OFF_WLO_E1 = OFF_WHI_E1 + S_W1;
constexpr size_t OFF_WHI_D0 = OFF_WLO_E1 + S_W1;
constexpr size_t OFF_WLO_D0 = OFF_WHI_D0 + S_W0;
constexpr size_t OFF_WHI_D1 = OFF_WLO_D0 + S_W0;
constexpr size_t OFF_WLO_D1 = OFF_WHI_D1 + S_W1;
constexpr size_t OFF_FCHI  = OFF_WLO_D1 + S_W1;
constexpr size_t OFF_FCLO  = OFF_FCHI + S_FC;
constexpr size_t OFF_XHI   = OFF_FCLO + S_FC;
constexpr size_t OFF_XLO   = OFF_XHI + S_X;
constexpr size_t OFF_DXHI  = OFF_XLO + S_X;
constexpr size_t OFF_DXLO  = OFF_DXHI + S_DX;
constexpr size_t OFF_H0HI  = OFF_DXLO + S_DX;   // memset from here down
constexpr size_t OFF_H0LO  = OFF_H0HI + S_H;
constexpr size_t OFF_H1HI  = OFF_H0LO + S_H;
constexpr size_t OFF_H1LO  = OFF_H1HI + S_H;
constexpr size_t OFF_C0    = OFF_H1LO + S_H;
constexpr size_t OFF_C1    = OFF_C0 + S_C;
constexpr size_t OFF_BAR   = OFF_C1 + S_C;
constexpr size_t OFF_END   = OFF_BAR + 4096;
constexpr size_t MEMSET_BYTES = OFF_END - OFF_H0HI;

// ---------------- bf16 split helpers ----------------
__device__ __forceinline__ u16 f2bf(float f) {
  u32 u = __float_as_uint(f);
  u += 0x7FFFu + ((u >> 16) & 1u);   // RNE
  return (u16)(u >> 16);
}
__device__ __forceinline__ float bf2f(u16 h) {
  return __uint_as_float(((u32)h) << 16);
}

__device__ __forceinline__ float sigf(float x) { return 1.f / (1.f + __expf(-x)); }
__device__ __forceinline__ float tanh_f(float x) {
  float xx = fminf(20.f, fmaxf(-20.f, x));
  float e = __expf(-2.f * xx);
  return (1.f - e) / (1.f + e);
}

__device__ __forceinline__ floatx4 mfma3(short8 ah, short8 al, short8 bh, short8 bl, floatx4 acc) {
  acc = __builtin_amdgcn_mfma_f32_16x16x32_bf16(ah, bh, acc, 0, 0, 0);
  acc = __builtin_amdgcn_mfma_f32_16x16x32_bf16(ah, bl, acc, 0, 0, 0);
  acc = __builtin_amdgcn_mfma_f32_16x16x32_bf16(al, bh, acc, 0, 0, 0);
  return acc;
}

// ---------------- prep kernels ----------------
// W concat: [Wih | Whh] along k, rows = 2048 gates, split into bf16 hi/lo, layout [gc][K]
__global__ void k_split_pair(const float* __restrict__ Wih, const float* __restrict__ Whh,
                             int ins, int K, u16* __restrict__ hi, u16* __restrict__ lo) {
  int n = NG * K;
  for (int idx = blockIdx.x * blockDim.x + threadIdx.x; idx < n; idx += gridDim.x * blockDim.x) {
    int row = idx / K;
    int k = idx - row * K;
    float v = (k < ins) ? Wih[row * ins + k] : Whh[row * HID + (k - ins)];
    u16 h = f2bf(v);
    hi[idx] = h;
    lo[idx] = f2bf(v - bf2f(h));
  }
}

__global__ void k_split_flat(const float* __restrict__ src, u16* __restrict__ hi,
                             u16* __restrict__ lo, int n) {
  for (int idx = blockIdx.x * blockDim.x + threadIdx.x; idx < n; idx += gridDim.x * blockDim.x) {
    float v = src[idx];
    u16 h = f2bf(v);
    hi[idx] = h;
    lo[idx] = f2bf(v - bf2f(h));
  }
}

// input_seq [B][T][F] -> [T][B][F] split; also init decoder x slot 0 from t=T-1
__global__ void k_split_x(const float* __restrict__ x, u16* __restrict__ xh, u16* __restrict__ xl,
                          u16* __restrict__ dxh, u16* __restrict__ dxl) {
  int n = BSZ * SEQT * FIN;
  for (int idx = blockIdx.x * blockDim.x + threadIdx.x; idx < n; idx += gridDim.x * blockDim.x) {
    int t = idx / (BSZ * FIN);
    int rem = idx - t * (BSZ * FIN);
    int b = rem >> 6;
    int f = rem & 63;
    float v = x[(b * SEQT + t) * FIN + f];
    u16 h = f2bf(v);
    u16 l = f2bf(v - bf2f(h));
    xh[idx] = h;
    xl[idx] = l;
    if (t == SEQT - 1) { dxh[(b << 6) + f] = h; dxl[(b << 6) + f] = l; }
  }
}

// ---------------- params ----------------
struct Params {
  const u16 *we0h, *we0l, *we1h, *we1l;
  const u16 *wd0h, *wd0l, *wd1h, *wd1l;
  const u16 *fch, *fcl;
  const u16 *xhi, *xlo;
  u16 *h0h, *h0l, *h1h, *h1l, *dxh, *dxl;
  float *c0, *c1;
  const float *beih0, *behh0, *beih1, *behh1;
  const float *bdih0, *bdhh0, *bdih1, *bdhh1;
  const float *fcb;
  float *out;
  u32 *bar;
};

// ---------------- grid barrier (2-level tree, monotonic counters) ----------------
__device__ __forceinline__ void grid_barrier(u32* bar, u32 gen) {
  __syncthreads();   // emits waitcnt vmcnt(0): all block stores complete at local L2
  if (threadIdx.x == 0) {
    __threadfence(); // agent-scope: writeback L2 so other XCDs can see our stores
    u32* leaf = bar + 16 + ((blockIdx.x & 15) << 4);  // 64B-spaced leaf counters
    u32 tgt = gen << 4;                               // 16 arrivals per leaf per gen
    u32 a = __hip_atomic_fetch_add(leaf, 1u, __ATOMIC_RELAXED, __HIP_MEMORY_SCOPE_AGENT) + 1u;
    if (a == tgt)
      __hip_atomic_fetch_add(bar, 1u, __ATOMIC_RELAXED, __HIP_MEMORY_SCOPE_AGENT); // 16 leaves/gen
    while (__hip_atomic_load(bar, __ATOMIC_RELAXED, __HIP_MEMORY_SCOPE_AGENT) < tgt)
      __builtin_amdgcn_s_sleep(1);
    (void)__hip_atomic_load(bar, __ATOMIC_ACQUIRE, __HIP_MEMORY_SCOPE_AGENT); // inv caches
  }
  __syncthreads();
}

// ---------------- W -> LDS (persistent) ----------------
// LDS layout: hi at [0], lo at [16*1024]. L1 rows use XOR-swizzled 16B chunks (stride 1024,
// power-of-2, conflict-free 2 lanes/bank-group); L0 rows use pad stride 584.
template <bool IS_L1>
__device__ void load_w_lds(const u16* __restrict__ gh, const u16* __restrict__ gl,
                           u16* wh, u16* wl, int hc) {
  constexpr int K = IS_L1 ? K1 : K0;
  for (int i = threadIdx.x; i < 16 * K; i += NTHR) {
    int rr, k;
    if (IS_L1) { rr = i >> 10; k = i & 1023; }
    else       { rr = i / K0;  k = i - rr * K0; }
    int gc = ((rr >> 2) * HID) + hc + (rr & 3);   // row r -> gate q=r>>2, col j=r&3
    int dst = IS_L1 ? ((rr << 10) + ((((k >> 3) ^ rr)) << 3) + (k & 7))
                    : (rr * K0P + k);
    wh[dst] = gh[(size_t)gc * K + k];
    wl[dst] = gl[(size_t)gc * K + k];
  }
  __syncthreads();
}

// ---------------- one LSTM layer step for this block's 4 h-columns ----------------
// A = [seg0 ; seg1(h, stride HID)], gates = A @ W^T + bih + bhh, then cell update.
template <bool IS_L1>
__device__ void layer_step(const u16* __restrict__ s0h, const u16* __restrict__ s0l,
                           const u16* __restrict__ s1h, const u16* __restrict__ s1l,
                           const u16* __restrict__ wh, const u16* __restrict__ wl,
                           const float* __restrict__ bih, const float* __restrict__ bhh,
                           float* __restrict__ cbuf,
                           u16* __restrict__ ohh, u16* __restrict__ ohl, int hc) {
  constexpr int LEN0 = IS_L1 ? HID : FIN;
  const int tid = threadIdx.x, lane = tid & 63, w = tid >> 6;
  const int quad = lane >> 4, r = lane & 15;
  const int m = (w << 4) + r;       // A row for this lane's fragment
  const int qo = quad << 3;
  floatx4 acc = {0.f, 0.f, 0.f, 0.f};

#pragma unroll 4
  for (int kk = 0; kk < LEN0; kk += 32) {
    const int ao = m * LEN0 + kk + qo;
    short8 ah = *(const short8*)(s0h + ao);
    short8 al = *(const short8*)(s0l + ao);
    int woff;
    if (IS_L1) { int c = (kk >> 3) + quad; woff = (r << 10) + ((c ^ r) << 3); }
    else       { woff = r * K0P + kk + qo; }
    short8 bh = *(const short8*)(wh + woff);
    short8 bl = *(const short8*)(wl + woff);
    acc = mfma3(ah, al, bh, bl, acc);
  }
#pragma unroll 4
  for (int kk = 0; kk < HID; kk += 32) {
    const int ao = m * HID + kk + qo;
    short8 ah = *(const short8*)(s1h + ao);
    short8 al = *(const short8*)(s1l + ao);
    const int kg = kk + LEN0;
    int woff;
    if (IS_L1) { int c = (kg >> 3) + quad; woff = (r << 10) + ((c ^ r) << 3); }
    else       { woff = r * K0P + kg + qo; }
    short8 bh = *(const short8*)(wh + woff);
    short8 bl = *(const short8*)(wl + woff);
    acc = mfma3(ah, al, bh, bl, acc);
  }

  // Epilogue: C[row=quad*4+i within wave tile][col=r]; redistribute so each lane owns
  // one (b, j) with its 4 gates, via shfl.
  const int j = lane & 3;
  const int rw = lane >> 2;        // row within wave tile
  const int b = (w << 4) + rw;
  const int isel = rw & 3;
  const int slb = lane & 48;       // (rw>>2)<<4 == (lane>>4)<<4
  float gate[4];
#pragma unroll
  for (int q = 0; q < 4; ++q) {
    const int sl = slb + (q << 2) + j;
    float t0 = __shfl(acc[0], sl, 64);
    float t1 = __shfl(acc[1], sl, 64);
    float t2 = __shfl(acc[2], sl, 64);
    float t3 = __shfl(acc[3], sl, 64);
    gate[q] = (isel == 0) ? t0 : (isel == 1) ? t1 : (isel == 2) ? t2 : t3;
  }

  const int ch = hc + j;
  const int idx = b * HID + ch;
  float iv = gate[0] + bih[ch] + bhh[ch];
  float fv = gate[1] + bih[HID + ch] + bhh[HID + ch];
  float gv = gate[2] + bih[2 * HID + ch] + bhh[2 * HID + ch];
  float ov = gate[3] + bih[3 * HID + ch] + bhh[3 * HID + ch];
  float co = cbuf[idx];
  float cn = fmaf(sigf(fv), co, sigf(iv) * tanh_f(gv));
  float hn = sigf(ov) * tanh_f(cn);
  cbuf[idx] = cn;
  u16 hh = f2bf(hn);
  ohh[idx] = hh;
  ohl[idx] = f2bf(hn - bf2f(hh));
}

// ---------------- decoder fc (blocks 0..3): out = dh1 @ fcW^T + fcb ----------------
__device__ void fc_step(int t, int blk,
                        const u16* __restrict__ ah, const u16* __restrict__ al,
                        const u16* __restrict__ fh, const u16* __restrict__ fl,
                        const float* __restrict__ fcb, float* __restrict__ out,
                        u16* __restrict__ dxh, u16* __restrict__ dxl) {
  const int tid = threadIdx.x, lane = tid & 63, w = tid >> 6;
  const int quad = lane >> 4, r = lane & 15;
  const int m = (w << 4) + r;
  const int qo = quad << 3;
  const int col = (blk << 4) + r;
  floatx4 acc = {0.f, 0.f, 0.f, 0.f};
#pragma unroll 4
  for (int kk = 0; kk < HID; kk += 32) {
    short8 a1 = *(const short8*)(ah + m * HID + kk + qo);
    short8 a2 = *(const short8*)(al + m * HID + kk + qo);
    short8 b1 = *(const short8*)(fh + col * HID + kk + qo);
    short8 b2 = *(const short8*)(fl + col * HID + kk + qo);
    acc = mfma3(a1, a2, b1, b2, acc);
  }
  float bias = fcb[col];
#pragma unroll
  for (int i = 0; i < 4; ++i) {
    int b = (w << 4) + (quad << 2) + i;
    float v = acc[i] + bias;
    out[(b * FUTL + t) * FIN + col] = v;
    u16 hv = f2bf(v);
    dxh[b * FIN + col] = hv;
    dxl[b * FIN + col] = f2bf(v - bf2f(hv));
  }
}

// ---------------- the persistent kernel ----------------
__global__ __launch_bounds__(NTHR, 1) void lstm_coop(Params p) {
  __shared__ u16 wsmem[32768];              // exactly 64 KB
  u16* wh = wsmem;
  u16* wl = wsmem + 16 * 1024;
  const int blk = blockIdx.x;
  const int grp = blk >> 7;                 // 0: layer0 role, 1: layer1 role
  const int hc = (blk & 127) << 2;          // this block's 4 h-columns
  u32 gen = 0;

  if (grp) load_w_lds<true>(p.we1h, p.we1l, wh, wl, hc);
  else     load_w_lds<false>(p.we0h, p.we0l, wh, wl, hc);

  // -------- encoder, wavefront: l0 at step s, l1 at step s-1 --------
  for (int s = 0; s <= SEQT; ++s) {
    if (!grp) {
      if (s < SEQT) {
        layer_step<false>(p.xhi + (size_t)s * (BSZ * FIN), p.xlo + (size_t)s * (BSZ * FIN),
                          p.h0h + ((s + 1) & 1) * (BSZ * HID), p.h0l + ((s + 1) & 1) * (BSZ * HID),
                          wh, wl, p.beih0, p.behh0, p.c0,
                          p.h0h + (s & 1) * (BSZ * HID), p.h0l + (s & 1) * (BSZ * HID), hc);
      }
    } else {
      if (s >= 1) {
        int t = s - 1;
        layer_step<true>(p.h0h + (t & 1) * (BSZ * HID), p.h0l + (t & 1) * (BSZ * HID),
                         p.h1h + ((t + 1) & 1) * (BSZ * HID), p.h1l + ((t + 1) & 1) * (BSZ * HID),
                         wh, wl, p.beih1, p.behh1, p.c1,
                         p.h1h + (t & 1) * (BSZ * HID), p.h1l + (t & 1) * (BSZ * HID), hc);
      }
    }
    ++gen;
    grid_barrier(p.bar, gen);
  }

  // -------- swap in decoder weights (block-local) --------
  if (grp) load_w_lds<true>(p.wd1h, p.wd1l, wh, wl, hc);
  else     load_w_lds<false>(p.wd0h, p.wd0l, wh, wl, hc);

  // -------- decoder: l0 -> barrier -> l1 -> barrier -> fc -> barrier --------
  // State buffers continue from encoder finals (same slices, slot parity lines up:
  // enc last write was slot 1, dec t=0 reads slot (t+1)&1 == 1).
  for (int t = 0; t < FUTL; ++t) {
    if (!grp) {
      layer_step<false>(p.dxh + (t & 1) * (BSZ * FIN), p.dxl + (t & 1) * (BSZ * FIN),
                        p.h0h + ((t + 1) & 1) * (BSZ * HID), p.h0l + ((t + 1) & 1) * (BSZ * HID),
                        wh, wl, p.bdih0, p.bdhh0, p.c0,
                        p.h0h + (t & 1) * (BSZ * HID), p.h0l + (t & 1) * (BSZ * HID), hc);
    }
    ++gen;
    grid_barrier(p.bar, gen);
    if (grp) {
      layer_step<true>(p.h0h + (t & 1) * (BSZ * HID), p.h0l + (t & 1) * (BSZ * HID),
                       p.h1h + ((t + 1) & 1) * (BSZ * HID), p.h1l + ((t + 1) & 1) * (BSZ * HID),
                       wh, wl, p.bdih1, p.bdhh1, p.c1,
                       p.h1h + (t & 1) * (BSZ * HID), p.h1l + (t & 1) * (BSZ * HID), hc);
    }
    ++gen;
    grid_barrier(p.bar, gen);
    if (blk < 4) {
      fc_step(t, blk, p.h1h + (t & 1) * (BSZ * HID), p.h1l + (t & 1) * (BSZ * HID),
              p.fch, p.fcl, p.fcb, p.out,
              p.dxh + ((t + 1) & 1) * (BSZ * FIN), p.dxl + ((t + 1) & 1) * (BSZ * FIN));
    }
    ++gen;
    grid_barrier(p.bar, gen);
  }
}

// ---------------- launch ----------------
extern "C" void kernel_launch(void* const* d_in, const int* in_sizes, int n_in,
                              void* d_out, int out_size, void* d_ws, size_t ws_size,
                              hipStream_t stream) {
  (void)in_sizes; (void)n_in; (void)out_size; (void)ws_size;
  const float* in_seq = (const float*)d_in[0];
  const float* eWih0 = (const float*)d_in[1];
  const float* eWhh0 = (const float*)d_in[2];
  const float* ebih0 = (const float*)d_in[3];
  const float* ebhh0 = (const float*)d_in[4];
  const float* eWih1 = (const float*)d_in[5];
  const float* eWhh1 = (const float*)d_in[6];
  const float* ebih1 = (const float*)d_in[7];
  const float* ebhh1 = (const float*)d_in[8];
  const float* dWih0 = (const float*)d_in[9];
  const float* dWhh0 = (const float*)d_in[10];
  const float* dbih0 = (const float*)d_in[11];
  const float* dbhh0 = (const float*)d_in[12];
  const float* dWih1 = (const float*)d_in[13];
  const float* dWhh1 = (const float*)d_in[14];
  const float* dbih1 = (const float*)d_in[15];
  const float* dbhh1 = (const float*)d_in[16];
  const float* fcW  = (const float*)d_in[17];
  const float* fcb  = (const float*)d_in[18];

  char* ws = (char*)d_ws;
  u16* we0h = (u16*)(ws + OFF_WHI_E0); u16* we0l = (u16*)(ws + OFF_WLO_E0);
  u16* we1h = (u16*)(ws + OFF_WHI_E1); u16* we1l = (u16*)(ws + OFF_WLO_E1);
  u16* wd0h = (u16*)(ws + OFF_WHI_D0); u16* wd0l = (u16*)(ws + OFF_WLO_D0);
  u16* wd1h = (u16*)(ws + OFF_WHI_D1); u16* wd1l = (u16*)(ws + OFF_WLO_D1);
  u16* fch  = (u16*)(ws + OFF_FCHI);   u16* fcl  = (u16*)(ws + OFF_FCLO);
  u16* xhi  = (u16*)(ws + OFF_XHI);    u16* xlo  = (u16*)(ws + OFF_XLO);
  u16* dxh  = (u16*)(ws + OFF_DXHI);   u16* dxl  = (u16*)(ws + OFF_DXLO);
  u16* h0h  = (u16*)(ws + OFF_H0HI);   u16* h0l  = (u16*)(ws + OFF_H0LO);
  u16* h1h  = (u16*)(ws + OFF_H1HI);   u16* h1l  = (u16*)(ws + OFF_H1LO);
  float* c0 = (float*)(ws + OFF_C0);   float* c1 = (float*)(ws + OFF_C1);
  u32* bar  = (u32*)(ws + OFF_BAR);

  // zero states + barrier counters (ws is poisoned 0xAA before every call)
  hipMemsetAsync(ws + OFF_H0HI, 0, MEMSET_BYTES, stream);

  k_split_pair<<<512, 256, 0, stream>>>(eWih0, eWhh0, FIN, K0, we0h, we0l);
  k_split_pair<<<512, 256, 0, stream>>>(eWih1, eWhh1, HID, K1, we1h, we1l);
  k_split_pair<<<512, 256, 0, stream>>>(dWih0, dWhh0, FIN, K0, wd0h, wd0l);
  k_split_pair<<<512, 256, 0, stream>>>(dWih1, dWhh1, HID, K1, wd1h, wd1l);
  k_split_flat<<<128, 256, 0, stream>>>(fcW, fch, fcl, FIN * HID);
  k_split_x<<<1024, 256, 0, stream>>>(in_seq, xhi, xlo, dxh, dxl);

  Params p;
  p.we0h = we0h; p.we0l = we0l; p.we1h = we1h; p.we1l = we1l;
  p.wd0h = wd0h; p.wd0l = wd0l; p.wd1h = wd1h; p.wd1l = wd1l;
  p.fch = fch; p.fcl = fcl;
  p.xhi = xhi; p.xlo = xlo;
  p.h0h = h0h; p.h0l = h0l; p.h1h = h1h; p.h1l = h1l;
  p.dxh = dxh; p.dxl = dxl;
  p.c0 = c0; p.c1 = c1;
  p.beih0 = ebih0; p.behh0 = ebhh0; p.beih1 = ebih1; p.behh1 = ebhh1;
  p.bdih0 = dbih0; p.bdhh0 = dbhh0; p.bdih1 = dbih1; p.bdhh1 = dbhh1;
  p.fcb = fcb;
  p.out = (float*)d_out;
  p.bar = bar;

  // 256 blocks x 256 threads: grid == CU count, 64KB LDS -> all blocks co-resident,
  // so the hand-rolled device-scope tree barrier is safe without cooperative launch.
  lstm_coop<<<dim3(NBLK), dim3(NTHR), 0, stream>>>(p);
}